// Round 14
// baseline (535.326 us; speedup 1.0000x reference)
//
#include <hip/hip_runtime.h>
#include <hip/hip_bf16.h>
#include <cstdint>
#include <cstddef>

typedef __hip_bfloat16 bf16;
typedef __bf16 bf16x8 __attribute__((ext_vector_type(8)));
typedef float f32x4 __attribute__((ext_vector_type(4)));

#define BB 2
#define TT 1024
#define CC 1024
#define HH 16
#define NP 512      // pairs per (b,h)
#define PRB 3072    // bytes per pair block in PK / LDS slot (768 floats, 706 used)
#define CH 4        // pairs per chunk
#define NCH 4       // chunks in LDS ring
#define CHB (CH * PRB)
#define NC (NP / CH)

__device__ __forceinline__ bf16 f2b(float v){ return __float2bfloat16(v); }

// 16-lane-row sum via DPP only (quad xor1, xor2, half_mirror ^4, row_mirror ^8).
__device__ __forceinline__ float hex_add(float x) {
    x += __int_as_float(__builtin_amdgcn_mov_dpp(__float_as_int(x), 0xB1, 0xF, 0xF, true));
    x += __int_as_float(__builtin_amdgcn_mov_dpp(__float_as_int(x), 0x4E, 0xF, 0xF, true));
    x += __int_as_float(__builtin_amdgcn_mov_dpp(__float_as_int(x), 0x141, 0xF, 0xF, true));
    x += __int_as_float(__builtin_amdgcn_mov_dpp(__float_as_int(x), 0x140, 0xF, 0xF, true));
    return x;
}

// async global -> LDS, 16B per lane (dest = wave-uniform base + lane*16, src per-lane)
typedef __attribute__((address_space(3))) void as3_void;
typedef __attribute__((address_space(1))) const void as1_void;
__device__ __forceinline__ void gload_lds16(const void* g, void* l) {
    __builtin_amdgcn_global_load_lds((as1_void*)g, (as3_void*)l, 16, 0, 0);
}

// ---------------- prep: 12 weight transposes + token-shift mix in ONE launch ----------------
struct TrDesc { const float* in; bf16* out; int R, S; };
struct PrepArgs {
    TrDesc d[12];
    const float* x; const float* vfirst;
    const float *mr, *mw, *mk, *mv, *ma, *mg;
    bf16 *xr, *xw, *xk, *xv, *xa, *xg;
    float* vout;
};

__global__ __launch_bounds__(256) void prep_kernel(PrepArgs args)
{
    if (blockIdx.z < 12) {
        TrDesc t = args.d[blockIdx.z];
        __shared__ float tile[32][33];
        int s0 = blockIdx.x * 32, r0 = blockIdx.y * 32;
        if (s0 >= t.S || r0 >= t.R) return;      // block-uniform early exit
        int tx = threadIdx.x & 31, ty = threadIdx.x >> 5;
#pragma unroll
        for (int i = 0; i < 4; i++) {
            int r = r0 + ty + i * 8, s = s0 + tx;
            if (r < t.R && s < t.S) tile[ty + i * 8][tx] = t.in[(size_t)r * t.S + s];
        }
        __syncthreads();
#pragma unroll
        for (int i = 0; i < 4; i++) {
            int s = s0 + ty + i * 8, r = r0 + tx;
            if (s < t.S && r < t.R) t.out[(size_t)s * t.R + r] = f2b(tile[tx][ty + i * 8]);
        }
        return;
    }
    // z == 12: token-shift mix, 2 rows per block
    int bid = blockIdx.y * 32 + blockIdx.x;
#pragma unroll
    for (int rr = 0; rr < 2; rr++) {
        int row = bid * 2 + rr;
        int t = row & (TT - 1);
        size_t base = (size_t)row * CC;
        for (int c = threadIdx.x; c < CC; c += 256) {
            float xc = args.x[base + c];
            float xp = (t > 0) ? args.x[base - CC + c] : 0.f;
            float d = xp - xc;
            args.xr[base + c] = f2b(xc + d * args.mr[c]);
            args.xw[base + c] = f2b(xc + d * args.mw[c]);
            args.xk[base + c] = f2b(xc + d * args.mk[c]);
            args.xv[base + c] = f2b(xc + d * args.mv[c]);
            args.xa[base + c] = f2b(xc + d * args.ma[c]);
            args.xg[base + c] = f2b(xc + d * args.mg[c]);
            args.vout[base + c] = args.vfirst[base + c];   // exact f32 passthrough
        }
    }
}

// ---------------- shared MFMA tile body: 2-phase double-buffered (round-10 proven) ----------------
template <class EmitF>
__device__ __forceinline__ void gemm_tile(const bf16* __restrict__ A, const bf16* __restrict__ BT,
                                          int K, int m0, int n0, EmitF emit)
{
    __shared__ __align__(16) bf16 Atile[2][128 * 32];
    __shared__ __align__(16) bf16 Btile[2][128 * 32];
    int tid = threadIdx.x;
    int w = tid >> 6, lane = tid & 63;
    int wr = w >> 1, wc = w & 1;
    int quad = lane >> 4, l16 = lane & 15;

    f32x4 zero = {0.f, 0.f, 0.f, 0.f};
    f32x4 acc[4][4];
#pragma unroll
    for (int i = 0; i < 4; i++)
#pragma unroll
        for (int j = 0; j < 4; j++) acc[i][j] = zero;

    int rr = lane >> 2;            // 0..15
    int cs = lane & 3;             // chunk slot in LDS
    int ra0 = w * 32 + rr;         // rows this lane sources
    int ra1 = ra0 + 16;
    int cg0 = cs ^ ((ra0 >> 1) & 3);   // global chunk (XOR swizzle on SOURCE side)
    int cg1 = cs ^ ((ra1 >> 1) & 3);

    const bf16* Ar0 = A  + (size_t)(m0 + ra0) * K + cg0 * 8;
    const bf16* Ar1 = A  + (size_t)(m0 + ra1) * K + cg1 * 8;
    const bf16* Br0 = BT + (size_t)(n0 + ra0) * K + cg0 * 8;
    const bf16* Br1 = BT + (size_t)(n0 + ra1) * K + cg1 * 8;

    auto stage = [&](int k0, int buf) {
        bf16* atb = Atile[buf] + w * 1024;   // wave-uniform LDS base (+lane*16B implicit)
        bf16* btb = Btile[buf] + w * 1024;
        gload_lds16(Ar0 + k0, atb);
        gload_lds16(Ar1 + k0, atb + 512);
        gload_lds16(Br0 + k0, btb);
        gload_lds16(Br1 + k0, btb + 512);
    };

    stage(0, 0);
    __syncthreads();               // tile 0 resident

    int cur = 0;
    for (int k0 = 0; k0 < K; k0 += 32) {
        if (k0 + 32 < K) stage(k0 + 32, cur ^ 1);   // in-flight across the compute below

        bf16x8 af[4], bfr[4];
#pragma unroll
        for (int mi = 0; mi < 4; mi++) {
            int m = wr * 64 + mi * 16 + l16;
            int c2 = quad ^ ((m >> 1) & 3);
            af[mi] = *reinterpret_cast<const bf16x8*>(&Atile[cur][m * 32 + c2 * 8]);
        }
#pragma unroll
        for (int ni = 0; ni < 4; ni++) {
            int n = wc * 64 + ni * 16 + l16;
            int c2 = quad ^ ((n >> 1) & 3);
            bfr[ni] = *reinterpret_cast<const bf16x8*>(&Btile[cur][n * 32 + c2 * 8]);
        }
#pragma unroll
        for (int mi = 0; mi < 4; mi++)
#pragma unroll
            for (int ni = 0; ni < 4; ni++)
                acc[mi][ni] = __builtin_amdgcn_mfma_f32_16x16x32_bf16(af[mi], bfr[ni], acc[mi][ni], 0, 0, 0);

        __syncthreads();           // drains vmcnt(0)+lgkm: next tile resident, reads done
        cur ^= 1;
    }

#pragma unroll
    for (int mi = 0; mi < 4; mi++)
#pragma unroll
        for (int ni = 0; ni < 4; ni++)
#pragma unroll
            for (int rg = 0; rg < 4; rg++) {
                int m = m0 + wr * 64 + mi * 16 + quad * 4 + rg;
                int n = n0 + wc * 64 + ni * 16 + l16;
                emit(m, n, acc[mi][ni][rg]);
            }
}

// ---------------- merged projections: big r/k/v (z 0..2) + lora stage 1 (z 3..6) ----------------
struct L1Desc { const bf16* A; const bf16* BT; bf16* outB; int N; int mode; }; // 0 plain, 2 tanh, 3 sigmoid
struct ProjArgs { const bf16* A[3]; const bf16* BT[3]; float* out[3]; L1Desc d[4]; };

__global__ __launch_bounds__(256) void proj_kernel(ProjArgs args)
{
    int z = blockIdx.z;
    if (z < 3) {
        float* out = args.out[z];
        gemm_tile(args.A[z], args.BT[z], 1024, blockIdx.x * 128, blockIdx.y * 128,
                  [&](int m, int n, float v) { out[(size_t)m * 1024 + n] = v; });
        return;
    }
    if (blockIdx.y) return;                   // lora1 output is <=128 wide (block-uniform exit)
    L1Desc dz = args.d[z - 3];
    gemm_tile(dz.A, dz.BT, 1024, blockIdx.x * 128, 0,
              [&](int m, int n, float v) {
                  if (n < dz.N) {
                      float r = (dz.mode == 2) ? tanhf(v)
                              : (dz.mode == 3) ? 1.f / (1.f + expf(-v)) : v;
                      dz.outB[(size_t)m * dz.N + n] = f2b(r);
                  }
              });
}

// ---------------- lora stage 2 (+g2): z-batched, N=1024, f32 out, fused epilogues ----------------
struct L2Desc { const bf16* A; const bf16* BT; const float* bias; float* outF; int K; int mode; };
struct L2Args { L2Desc d[4]; const float* vraw; const float* vfirst; };
__global__ __launch_bounds__(256) void lora2_kernel(L2Args args)
{
    L2Desc dz = args.d[blockIdx.z];
    gemm_tile(dz.A, dz.BT, dz.K, blockIdx.x * 128, blockIdx.y * 128,
              [&](int m, int n, float v) {
                  size_t idx = (size_t)m * 1024 + n;
                  if (dz.mode == 4) {
                      float xx = v + dz.bias[n];
                      float ww = -log1pf(expf(-xx)) - 0.5f;   // -softplus(-x) - 0.5
                      dz.outF[idx] = expf(-expf(ww));
                  } else if (dz.mode == 5) {
                      float xx = v + dz.bias[n];
                      dz.outF[idx] = 1.f / (1.f + expf(-xx));
                  } else if (dz.mode == 6) {
                      float gate = 1.f / (1.f + expf(-(v + dz.bias[n])));
                      float vr = args.vraw[idx];
                      dz.outF[idx] = vr + (args.vfirst[idx] - vr) * gate;
                  } else {
                      dz.outF[idx] = v;
                  }
              });
}

// ---------------- final output projection ----------------
__global__ __launch_bounds__(256) void final_kernel(const bf16* __restrict__ A, const bf16* __restrict__ BT,
                                                    float* __restrict__ out)
{
    gemm_tile(A, BT, 1024, blockIdx.x * 128, blockIdx.y * 128,
              [&](int m, int n, float v) { out[(size_t)m * 1024 + n] = v; });
}

// ---------------- pack: per-PAIR precompute for the double-step scan ----------------
// One wave per (b, tp, h) pair (t=2tp, t+1). Step map: row <- row(D+A B^T) + v_i k,
// A=-kkn, B=kkn*a. Pair fold (exact algebra):
//   d2 = d0*d1;  Bt~ = d1*B0;  A~ = d0*A1 + (B0.A1)*A0;  k~ = d1*ks0 + (ks0.A1)*B1;
//   r~ = d0*r0;  beta = B0.r0;  gamma = ks0.r0.
// PK pair slot (768 floats): k~[0] ks1[64] A0[128] A~[192] Bt~[256] B1[320]
//                            r~[384] r1[448] d2[512] v0[576] v1[640] beta@704 gamma@705
__global__ __launch_bounds__(256) void pack_kernel(
    float* __restrict__ k, const float* __restrict__ a, const float* __restrict__ r,
    const float* __restrict__ v, const float* __restrict__ dw,
    const float* __restrict__ kkw, const float* __restrict__ kaw,
    float* __restrict__ PK)
{
    int tid = threadIdx.x;
    int wave = tid >> 6, lane = tid & 63;
    int idx = blockIdx.x * 4 + wave;        // (b*NP + tp)*HH + h
    int b  = idx >> 13;
    int tp = (idx >> 4) & (NP - 1);
    int h  = idx & 15;
    size_t off0 = ((size_t)(b * TT + 2 * tp) * HH + h) * 64 + lane;
    size_t off1 = off0 + 1024;
    float kkw_l = kkw[h * 64 + lane];
    float kaw_l = kaw[h * 64 + lane];

    float k0 = k[off0], a0 = a[off0], r0 = r[off0], v0 = v[off0], d0 = dw[off0];
    float k1 = k[off1], a1 = a[off1], r1 = r[off1], v1 = v[off1], d1 = dw[off1];

    float kk0 = k0 * kkw_l, kk1 = k1 * kkw_l;
    float ks0 = k0 * fmaf(a0 - 1.f, kaw_l, 1.f);
    float ks1 = k1 * fmaf(a1 - 1.f, kaw_l, 1.f);
    k[off0] = ks0; k[off1] = ks1;           // write-back for gn_kernel

    float s0 = kk0 * kk0, s1 = kk1 * kk1;
#pragma unroll
    for (int m = 32; m; m >>= 1) { s0 += __shfl_xor(s0, m); s1 += __shfl_xor(s1, m); }
    float kn0 = kk0 / fmaxf(sqrtf(s0), 1e-12f);
    float kn1 = kk1 / fmaxf(sqrtf(s1), 1e-12f);
    float A0 = -kn0, A1 = -kn1;
    float B0 = kn0 * a0, B1 = kn1 * a1;

    float cBA = B0 * A1, cKA = ks0 * A1, beta = B0 * r0, gamma = ks0 * r0;
#pragma unroll
    for (int m = 32; m; m >>= 1) {
        cBA += __shfl_xor(cBA, m); cKA += __shfl_xor(cKA, m);
        beta += __shfl_xor(beta, m); gamma += __shfl_xor(gamma, m);
    }

    float At = fmaf(cBA, A0, d0 * A1);      // A~
    float Bt = d1 * B0;                      // Bt~
    float kt = fmaf(cKA, B1, d1 * ks0);      // k~
    float rt = d0 * r0;                      // r~
    float d2 = d0 * d1;

    size_t sidx = ((size_t)(b * HH + h) * NP + tp);
    float* pw = PK + sidx * 768;
    pw[lane] = kt;        pw[64 + lane]  = ks1;
    pw[128 + lane] = A0;  pw[192 + lane] = At;
    pw[256 + lane] = Bt;  pw[320 + lane] = B1;
    pw[384 + lane] = rt;  pw[448 + lane] = r1;
    pw[512 + lane] = d2;  pw[576 + lane] = v0;  pw[640 + lane] = v1;
    if (lane == 0) { pw[704] = beta; pw[705] = gamma; }
}

// ---------------- sequential state recurrence: double-step pairs, producer/consumer ----------------
// Grid 512 = 32 bh x 16 row-blocks (XCD-grouped). Wave0 computes 512 PAIRS (2 steps
// each); waves 1-3 stage 4-pair chunks into a 4-chunk LDS ring (counted vmcnt, raw
// s_barrier -- the proven round-5/8/10 skeleton, constants rescaled to pairs).
struct SetP { f32x4 kt, k1, A, At, Bt, B1, rt, r1, d2; float v0, v1; float2 bg; };

__device__ __forceinline__ void ds_load_pair(SetP& s, const char* slot, int c16, int row)
{
    s.A  = *(const f32x4*)(slot + 512  + c16);
    s.At = *(const f32x4*)(slot + 768  + c16);
    s.rt = *(const f32x4*)(slot + 1536 + c16);
    s.d2 = *(const f32x4*)(slot + 2048 + c16);
    s.Bt = *(const f32x4*)(slot + 1024 + c16);
    s.B1 = *(const f32x4*)(slot + 1280 + c16);
    s.kt = *(const f32x4*)(slot + 0    + c16);
    s.k1 = *(const f32x4*)(slot + 256  + c16);
    s.r1 = *(const f32x4*)(slot + 1792 + c16);
    s.v0 = *(const float*)(slot + 2304 + row * 4);
    s.v1 = *(const float*)(slot + 2560 + row * 4);
    s.bg = *(const float2*)(slot + 2816);
}

__device__ __forceinline__ void step_pair(const SetP& sd, f32x4& S, float& o1, float& o2)
{
    f32x4 pv = S * sd.A;
    f32x4 qv = S * sd.At;
    f32x4 rv = S * sd.rt;
    float p  = hex_add((pv[0] + pv[1]) + (pv[2] + pv[3]));
    float q  = hex_add((qv[0] + qv[1]) + (qv[2] + qv[3]));
    float ro = hex_add((rv[0] + rv[1]) + (rv[2] + rv[3]));
    o1 = fmaf(sd.v0, sd.bg.y, fmaf(p, sd.bg.x, ro));
    S = S * sd.d2 + p * sd.Bt + q * sd.B1 + sd.v0 * sd.kt + sd.v1 * sd.k1;
    f32x4 ov = S * sd.r1;
    o2 = hex_add((ov[0] + ov[1]) + (ov[2] + ov[3]));
}

__global__ __launch_bounds__(256, 1) void scan_kernel(
    const float* __restrict__ PK, float* __restrict__ ybuf)
{
    __shared__ __align__(16) char ring[NCH * CHB];   // 4 chunks x 4 pairs x 3KB = 48KB
    const int tid = threadIdx.x;
    const int wid = tid >> 6, lane = tid & 63;
    // XCD-grouped bijective decode (grid 512): all 16 row-blocks of a head on one XCD.
    const int xcd = blockIdx.x & 7, kk = blockIdx.x >> 3;
    const int bh = xcd * 4 + (kk >> 4);      // 0..31
    const int wq = kk & 15;                  // row-block 0..15
    const int b = bh >> 4, h = bh & 15;
    const int row = wq * 4 + (lane >> 4);    // 0..63 (compute wave semantics)
    const int c = lane & 15;
    const int c16 = c * 16;

    const char* base = (const char*)(PK + (size_t)bh * NP * 768);
    const char* gl = base + lane * 16;       // per-lane source within each 1KB segment

    // loader: wave wid (1..3) stages pairs j of chunk ci; wid1: j=0,3 (6 loads),
    // wid2: j=1 (3), wid3: j=2 (3). Each pair = 3 x 1KB segments.
    auto stage_chunk = [&](int ci) {
        for (int j = wid - 1; j < CH; j += 3) {
            const char* p = gl + (size_t)(ci * CH + j) * PRB;
            char* s = ring + (ci & (NCH - 1)) * CHB + j * PRB;
            gload_lds16(p,        s);
            gload_lds16(p + 1024, s + 1024);
            gload_lds16(p + 2048, s + 2048);
        }
    };

    if (wid > 0) {
        stage_chunk(0);
        stage_chunk(1);
        stage_chunk(2);
        asm volatile("s_waitcnt vmcnt(0)" ::: "memory");   // prologue: full drain once
    }
    __builtin_amdgcn_sched_barrier(0);
    __builtin_amdgcn_s_barrier();            // publishes chunks 0-2
    __builtin_amdgcn_sched_barrier(0);

    f32x4 S = {0.f, 0.f, 0.f, 0.f};
    SetP X, Y;
    if (wid == 0) ds_load_pair(X, ring, c16, row);
    float* py = ybuf + (size_t)b * TT * CC + h * 64 + row;

    for (int i = 0; i < NC; i++) {
        if (wid == 0) {
            const char* sl  = ring + (i & (NCH - 1)) * CHB;
            const char* sln = ring + ((i + 1) & (NCH - 1)) * CHB;
            float o1, o2;
            // 4 pairs, 2-set pipe: load next pair's set, compute current.
            ds_load_pair(Y, sl + 1 * PRB, c16, row);
            step_pair(X, S, o1, o2);
            if (c == 0) { py[0] = o1; py[CC] = o2; } py += 2 * CC;
            ds_load_pair(X, sl + 2 * PRB, c16, row);
            step_pair(Y, S, o1, o2);
            if (c == 0) { py[0] = o1; py[CC] = o2; } py += 2 * CC;
            ds_load_pair(Y, sl + 3 * PRB, c16, row);
            step_pair(X, S, o1, o2);
            if (c == 0) { py[0] = o1; py[CC] = o2; } py += 2 * CC;
            ds_load_pair(X, sln, c16, row);
            step_pair(Y, S, o1, o2);
            if (c == 0) { py[0] = o1; py[CC] = o2; } py += 2 * CC;
            // i == NC-1: sln pair0 is stale; loaded into X, never consumed
        } else {
            if (i + 3 < NC) {
                stage_chunk(i + 3);
                // counted wait: covers chunk i+2 (issued last iteration, latency hidden
                // under a full chunk of compute); chunk i+3 stays in flight.
                if (wid == 1) asm volatile("s_waitcnt vmcnt(6)" ::: "memory");
                else          asm volatile("s_waitcnt vmcnt(3)" ::: "memory");
            } else {
                asm volatile("s_waitcnt vmcnt(0)" ::: "memory");   // epilogue drain (cheap)
            }
        }
        __builtin_amdgcn_sched_barrier(0);
        __builtin_amdgcn_s_barrier();        // publishes chunk i+2 (and older)
        __builtin_amdgcn_sched_barrier(0);
    }
}

// ---------------- groupnorm + residual + gate -> z (bf16), 4 heads/block ----------------
__global__ __launch_bounds__(256) void gn_kernel(
    const float* __restrict__ y, const float* __restrict__ r, const float* __restrict__ k,
    const float* __restrict__ v, const float* __restrict__ g,
    const float* __restrict__ lnw, const float* __restrict__ lnb,
    const float* __restrict__ rk, bf16* __restrict__ z)
{
    int tid = threadIdx.x;
    int idx = blockIdx.x * 4 + (tid >> 6);   // (b*T+t)*16 + h
    int lane = tid & 63;
    size_t off = (size_t)idx * 64 + lane;
    int c = (idx & 15) * 64 + lane;
    float yv = y[off];
    float rv = r[off], kv = k[off], vv = v[off];
    float s1 = yv, s2 = yv * yv, s3 = rv * kv * rk[c];
#pragma unroll
    for (int m = 32; m; m >>= 1) {
        s1 += __shfl_xor(s1, m);
        s2 += __shfl_xor(s2, m);
        s3 += __shfl_xor(s3, m);
    }
    float mu = s1 * (1.f / 64.f);
    float var = fmaxf(s2 * (1.f / 64.f) - mu * mu, 0.f);
    float yn = (yv - mu) * rsqrtf(var + 64e-5f) * lnw[c] + lnb[c];
    float out = (yn + s3 * vv) * g[off];
    z[off] = f2b(out);
}

// ---------------- host ----------------
extern "C" void kernel_launch(void* const* d_in, const int* in_sizes, int n_in,
                              void* d_out, int out_size, void* d_ws, size_t ws_size,
                              hipStream_t stream)
{
    const float* x       = (const float*)d_in[0];
    const float* v_first = (const float*)d_in[1];
    const float* x_r = (const float*)d_in[2];
    const float* x_w = (const float*)d_in[3];
    const float* x_k = (const float*)d_in[4];
    const float* x_v = (const float*)d_in[5];
    const float* x_a = (const float*)d_in[6];
    const float* x_g = (const float*)d_in[7];
    const float* w1 = (const float*)d_in[8];
    const float* w2 = (const float*)d_in[9];
    const float* w0 = (const float*)d_in[10];
    const float* a1 = (const float*)d_in[11];
    const float* a2 = (const float*)d_in[12];
    const float* a0 = (const float*)d_in[13];
    const float* v1 = (const float*)d_in[14];
    const float* v2 = (const float*)d_in[15];
    const float* v0 = (const float*)d_in[16];
    const float* g1 = (const float*)d_in[17];
    const float* g2 = (const float*)d_in[18];
    const float* k_k = (const float*)d_in[19];
    const float* k_a = (const float*)d_in[20];
    const float* r_k = (const float*)d_in[21];
    const float* W_r = (const float*)d_in[22];
    const float* W_k = (const float*)d_in[23];
    const float* W_v = (const float*)d_in[24];
    const float* W_o = (const float*)d_in[25];
    const float* ln_w = (const float*)d_in[26];
    const float* ln_b = (const float*)d_in[27];

    const size_t BTC = (size_t)BB * TT * CC;   // 2M
    const int M = BB * TT;                     // 2048

    char* ws = (char*)d_ws;
    size_t off = 0;
    auto alloc = [&](size_t bytes) -> char* {
        char* p = ws + off;
        off += (bytes + 255) & ~(size_t)255;
        return p;
    };

    // ---- region0: everything here is dead before pack_kernel; PK aliases it ----
    bf16* xr = (bf16*)alloc(BTC * 2);
    bf16* xw = (bf16*)alloc(BTC * 2);
    bf16* xk = (bf16*)alloc(BTC * 2);
    bf16* xv = (bf16*)alloc(BTC * 2);
    bf16* xa = (bf16*)alloc(BTC * 2);
    bf16* xg = (bf16*)alloc(BTC * 2);
    bf16* WrT = (bf16*)alloc(1024 * 1024 * 2);
    bf16* WkT = (bf16*)alloc(1024 * 1024 * 2);
    bf16* WvT = (bf16*)alloc(1024 * 1024 * 2);
    bf16* w1T = (bf16*)alloc(128 * 1024 * 2);   // 64 rows used, pad benign
    bf16* a1T = (bf16*)alloc(128 * 1024 * 2);
    bf16* v1T = (bf16*)alloc(128 * 1024 * 2);   // 32 rows used
    bf16* g1T = (bf16*)alloc(128 * 1024 * 2);
    bf16* w2T = (bf16*)alloc(1024 * 64 * 2);
    bf16* a2T = (bf16*)alloc(1024 * 64 * 2);
    bf16* v2T = (bf16*)alloc(1024 * 32 * 2);
    bf16* g2T = (bf16*)alloc(1024 * 128 * 2);
    bf16* h_w = (bf16*)alloc((size_t)M * 64 * 2);
    bf16* h_a = (bf16*)alloc((size_t)M * 64 * 2);
    bf16* h_v = (bf16*)alloc((size_t)M * 32 * 2);
    bf16* h_g = (bf16*)alloc((size_t)M * 128 * 2);

    // PK aliases region0; pairs: 32 bh x 512 x 3072B = 50,331,648
    float* PK = (float*)ws;
    size_t pk_end = (size_t)BB * HH * NP * PRB;
    if (off < pk_end) off = pk_end;
    off = (off + 255) & ~(size_t)255;

    // ---- live across pack/scan ----
    bf16* WoT = (bf16*)alloc(1024 * 1024 * 2);
    float* rbuf = (float*)alloc(BTC * 4);
    float* kbuf = (float*)alloc(BTC * 4);
    float* vraw = (float*)alloc(BTC * 4);   // reused as ybuf after lora2
    float* vbuf = (float*)alloc(BTC * 4);
    float* dbuf = (float*)alloc(BTC * 4);   // reused as zbuf (bf16) after scan
    float* abuf = (float*)alloc(BTC * 4);
    float* gbuf = (float*)alloc(BTC * 4);

    float* ybuf = vraw;
    bf16*  zbuf = (bf16*)dbuf;

    (void)in_sizes; (void)n_in; (void)out_size; (void)ws_size;

    // 1) transposes + token-shift mix in one launch
    PrepArgs pa;
    pa.d[0]  = {W_r, WrT, 1024, 1024};
    pa.d[1]  = {W_k, WkT, 1024, 1024};
    pa.d[2]  = {W_v, WvT, 1024, 1024};
    pa.d[3]  = {W_o, WoT, 1024, 1024};
    pa.d[4]  = {w1, w1T, 1024, 64};
    pa.d[5]  = {a1, a1T, 1024, 64};
    pa.d[6]  = {v1, v1T, 1024, 32};
    pa.d[7]  = {g1, g1T, 1024, 128};
    pa.d[8]  = {w2, w2T, 64, 1024};
    pa.d[9]  = {a2, a2T, 64, 1024};
    pa.d[10] = {v2, v2T, 32, 1024};
    pa.d[11] = {g2, g2T, 128, 1024};
    pa.x = x; pa.vfirst = v_first;
    pa.mr = x_r; pa.mw = x_w; pa.mk = x_k; pa.mv = x_v; pa.ma = x_a; pa.mg = x_g;
    pa.xr = xr; pa.xw = xw; pa.xk = xk; pa.xv = xv; pa.xa = xa; pa.xg = xg;
    pa.vout = (float*)d_out + BTC;
    prep_kernel<<<dim3(32, 32, 13), 256, 0, stream>>>(pa);

    // 2) big projections r/k/v + lora stage 1, one launch
    ProjArgs pj;
    pj.A[0] = xr; pj.A[1] = xk; pj.A[2] = xv;
    pj.BT[0] = WrT; pj.BT[1] = WkT; pj.BT[2] = WvT;
    pj.out[0] = rbuf; pj.out[1] = kbuf; pj.out[2] = vraw;
    pj.d[0] = {xw, w1T, h_w, 64, 2};
    pj.d[1] = {xa, a1T, h_a, 64, 0};
    pj.d[2] = {xv, v1T, h_v, 32, 0};
    pj.d[3] = {xg, g1T, h_g, 128, 3};
    proj_kernel<<<dim3(16, 8, 7), 256, 0, stream>>>(pj);

    // 3) lora stage 2 + g2
    L2Args l2;
    l2.d[0] = {h_w, w2T, w0, dbuf, 64, 4};
    l2.d[1] = {h_a, a2T, a0, abuf, 64, 5};
    l2.d[2] = {h_v, v2T, v0, vbuf, 32, 6};
    l2.d[3] = {h_g, g2T, nullptr, gbuf, 128, 0};
    l2.vraw = vraw; l2.vfirst = v_first;
    lora2_kernel<<<dim3(16, 8, 4), 256, 0, stream>>>(l2);

    // 4) pack pairs (double-step precompute; writes scaled k back to kbuf)
    pack_kernel<<<BB * NP * HH / 4, 256, 0, stream>>>(kbuf, abuf, rbuf, vbuf, dbuf, k_k, k_a, PK);

    // 5) sequential recurrence over 512 pairs (producer/consumer, counted vmcnt)
    scan_kernel<<<BB * HH * 16, 256, 0, stream>>>(PK, ybuf);

    // 6) groupnorm + residual + gate (writes zbuf = dbuf region)
    gn_kernel<<<BB * TT * HH / 4, 256, 0, stream>>>(ybuf, rbuf, kbuf, vbuf, gbuf, ln_w, ln_b, r_k, zbuf);

    // 7) output projection -> d_out (f32)
    final_kernel<<<dim3(16, 8), 256, 0, stream>>>(zbuf, WoT, (float*)d_out);
}

// Round 15
// 411.512 us; speedup vs baseline: 1.3009x; 1.3009x over previous
//
#include <hip/hip_runtime.h>
#include <hip/hip_bf16.h>
#include <cstdint>
#include <cstddef>

typedef __hip_bfloat16 bf16;
typedef __bf16 bf16x8 __attribute__((ext_vector_type(8)));
typedef float f32x4 __attribute__((ext_vector_type(4)));

#define BB 2
#define TT 1024
#define CC 1024
#define HH 16
#define PKS 448   // floats per (bh,t) block: k[64] kk[64] bb[64] v[64] r[64] d[64] bt ct pad
#define PKB 1792  // bytes per block (448*4)
#define CH 8      // steps per chunk
#define NCH 4     // chunks in LDS ring
#define STEPB 2048  // bytes per step slot in LDS
#define CHB (CH * STEPB)
#define NC (TT / CH)

__device__ __forceinline__ bf16 f2b(float v){ return __float2bfloat16(v); }

// 16-lane-row sum via DPP only (quad xor1, xor2, half_mirror ^4, row_mirror ^8).
__device__ __forceinline__ float hex_add(float x) {
    x += __int_as_float(__builtin_amdgcn_mov_dpp(__float_as_int(x), 0xB1, 0xF, 0xF, true));
    x += __int_as_float(__builtin_amdgcn_mov_dpp(__float_as_int(x), 0x4E, 0xF, 0xF, true));
    x += __int_as_float(__builtin_amdgcn_mov_dpp(__float_as_int(x), 0x141, 0xF, 0xF, true));
    x += __int_as_float(__builtin_amdgcn_mov_dpp(__float_as_int(x), 0x140, 0xF, 0xF, true));
    return x;
}

// async global -> LDS, 16B per lane (dest = wave-uniform base + lane*16, src per-lane)
typedef __attribute__((address_space(3))) void as3_void;
typedef __attribute__((address_space(1))) const void as1_void;
__device__ __forceinline__ void gload_lds16(const void* g, void* l) {
    __builtin_amdgcn_global_load_lds((as1_void*)g, (as3_void*)l, 16, 0, 0);
}

// ---------------- prep: 12 weight transposes + token-shift mix in ONE launch ----------------
struct TrDesc { const float* in; bf16* out; int R, S; };
struct PrepArgs {
    TrDesc d[12];
    const float* x; const float* vfirst;
    const float *mr, *mw, *mk, *mv, *ma, *mg;
    bf16 *xr, *xw, *xk, *xv, *xa, *xg;
    float* vout;
};

__global__ __launch_bounds__(256) void prep_kernel(PrepArgs args)
{
    if (blockIdx.z < 12) {
        TrDesc t = args.d[blockIdx.z];
        __shared__ float tile[32][33];
        int s0 = blockIdx.x * 32, r0 = blockIdx.y * 32;
        if (s0 >= t.S || r0 >= t.R) return;      // block-uniform early exit
        int tx = threadIdx.x & 31, ty = threadIdx.x >> 5;
#pragma unroll
        for (int i = 0; i < 4; i++) {
            int r = r0 + ty + i * 8, s = s0 + tx;
            if (r < t.R && s < t.S) tile[ty + i * 8][tx] = t.in[(size_t)r * t.S + s];
        }
        __syncthreads();
#pragma unroll
        for (int i = 0; i < 4; i++) {
            int s = s0 + ty + i * 8, r = r0 + tx;
            if (s < t.S && r < t.R) t.out[(size_t)s * t.R + r] = f2b(tile[tx][ty + i * 8]);
        }
        return;
    }
    // z == 12: token-shift mix, 2 rows per block
    int bid = blockIdx.y * 32 + blockIdx.x;
#pragma unroll
    for (int rr = 0; rr < 2; rr++) {
        int row = bid * 2 + rr;
        int t = row & (TT - 1);
        size_t base = (size_t)row * CC;
        for (int c = threadIdx.x; c < CC; c += 256) {
            float xc = args.x[base + c];
            float xp = (t > 0) ? args.x[base - CC + c] : 0.f;
            float d = xp - xc;
            args.xr[base + c] = f2b(xc + d * args.mr[c]);
            args.xw[base + c] = f2b(xc + d * args.mw[c]);
            args.xk[base + c] = f2b(xc + d * args.mk[c]);
            args.xv[base + c] = f2b(xc + d * args.mv[c]);
            args.xa[base + c] = f2b(xc + d * args.ma[c]);
            args.xg[base + c] = f2b(xc + d * args.mg[c]);
            args.vout[base + c] = args.vfirst[base + c];   // exact f32 passthrough
        }
    }
}

// ---------------- shared MFMA tile body: 2-phase double-buffered (round-10 proven) ----------------
template <class EmitF>
__device__ __forceinline__ void gemm_tile(const bf16* __restrict__ A, const bf16* __restrict__ BT,
                                          int K, int m0, int n0, EmitF emit)
{
    __shared__ __align__(16) bf16 Atile[2][128 * 32];
    __shared__ __align__(16) bf16 Btile[2][128 * 32];
    int tid = threadIdx.x;
    int w = tid >> 6, lane = tid & 63;
    int wr = w >> 1, wc = w & 1;
    int quad = lane >> 4, l16 = lane & 15;

    f32x4 zero = {0.f, 0.f, 0.f, 0.f};
    f32x4 acc[4][4];
#pragma unroll
    for (int i = 0; i < 4; i++)
#pragma unroll
        for (int j = 0; j < 4; j++) acc[i][j] = zero;

    int rr = lane >> 2;            // 0..15
    int cs = lane & 3;             // chunk slot in LDS
    int ra0 = w * 32 + rr;         // rows this lane sources
    int ra1 = ra0 + 16;
    int cg0 = cs ^ ((ra0 >> 1) & 3);   // global chunk (XOR swizzle on SOURCE side)
    int cg1 = cs ^ ((ra1 >> 1) & 3);

    const bf16* Ar0 = A  + (size_t)(m0 + ra0) * K + cg0 * 8;
    const bf16* Ar1 = A  + (size_t)(m0 + ra1) * K + cg1 * 8;
    const bf16* Br0 = BT + (size_t)(n0 + ra0) * K + cg0 * 8;
    const bf16* Br1 = BT + (size_t)(n0 + ra1) * K + cg1 * 8;

    auto stage = [&](int k0, int buf) {
        bf16* atb = Atile[buf] + w * 1024;   // wave-uniform LDS base (+lane*16B implicit)
        bf16* btb = Btile[buf] + w * 1024;
        gload_lds16(Ar0 + k0, atb);
        gload_lds16(Ar1 + k0, atb + 512);
        gload_lds16(Br0 + k0, btb);
        gload_lds16(Br1 + k0, btb + 512);
    };

    stage(0, 0);
    __syncthreads();               // tile 0 resident

    int cur = 0;
    for (int k0 = 0; k0 < K; k0 += 32) {
        if (k0 + 32 < K) stage(k0 + 32, cur ^ 1);   // in-flight across the compute below

        bf16x8 af[4], bfr[4];
#pragma unroll
        for (int mi = 0; mi < 4; mi++) {
            int m = wr * 64 + mi * 16 + l16;
            int c2 = quad ^ ((m >> 1) & 3);
            af[mi] = *reinterpret_cast<const bf16x8*>(&Atile[cur][m * 32 + c2 * 8]);
        }
#pragma unroll
        for (int ni = 0; ni < 4; ni++) {
            int n = wc * 64 + ni * 16 + l16;
            int c2 = quad ^ ((n >> 1) & 3);
            bfr[ni] = *reinterpret_cast<const bf16x8*>(&Btile[cur][n * 32 + c2 * 8]);
        }
#pragma unroll
        for (int mi = 0; mi < 4; mi++)
#pragma unroll
            for (int ni = 0; ni < 4; ni++)
                acc[mi][ni] = __builtin_amdgcn_mfma_f32_16x16x32_bf16(af[mi], bfr[ni], acc[mi][ni], 0, 0, 0);

        __syncthreads();           // drains vmcnt(0)+lgkm: next tile resident, reads done
        cur ^= 1;
    }

#pragma unroll
    for (int mi = 0; mi < 4; mi++)
#pragma unroll
        for (int ni = 0; ni < 4; ni++)
#pragma unroll
            for (int rg = 0; rg < 4; rg++) {
                int m = m0 + wr * 64 + mi * 16 + quad * 4 + rg;
                int n = n0 + wc * 64 + ni * 16 + l16;
                emit(m, n, acc[mi][ni][rg]);
            }
}

// ---------------- merged projections: big r/k/v (z 0..2) + lora stage 1 (z 3..6) ----------------
struct L1Desc { const bf16* A; const bf16* BT; bf16* outB; int N; int mode; }; // 0 plain, 2 tanh, 3 sigmoid
struct ProjArgs { const bf16* A[3]; const bf16* BT[3]; float* out[3]; L1Desc d[4]; };

__global__ __launch_bounds__(256) void proj_kernel(ProjArgs args)
{
    int z = blockIdx.z;
    if (z < 3) {
        float* out = args.out[z];
        gemm_tile(args.A[z], args.BT[z], 1024, blockIdx.x * 128, blockIdx.y * 128,
                  [&](int m, int n, float v) { out[(size_t)m * 1024 + n] = v; });
        return;
    }
    if (blockIdx.y) return;                   // lora1 output is <=128 wide (block-uniform exit)
    L1Desc dz = args.d[z - 3];
    gemm_tile(dz.A, dz.BT, 1024, blockIdx.x * 128, 0,
              [&](int m, int n, float v) {
                  if (n < dz.N) {
                      float r = (dz.mode == 2) ? tanhf(v)
                              : (dz.mode == 3) ? 1.f / (1.f + expf(-v)) : v;
                      dz.outB[(size_t)m * dz.N + n] = f2b(r);
                  }
              });
}

// ---------------- lora stage 2 (+g2): REGISTER-DIRECT small-K GEMM ----------------
// ROUND-15: K in {32,64,128} means the LDS-staged 2-phase template is all prologue
// (1-4 K-steps, each behind a full vmcnt(0) barrier drain) -- profile: 147us,
// MfmaUtil 0.3%, ~99% stalled. Fix: load MFMA fragments STRAIGHT from global (the
// swizzled-LDS read provably unwinds to A[(m0+m)*K + k0 + quad*8] -- identical
// bytes), no LDS, no __syncthreads, nothing to stall on. B is L2-resident (<=256KB).
struct L2Desc { const bf16* A; const bf16* BT; const float* bias; float* outF; int K; int mode; };
struct L2Args { L2Desc d[4]; const float* vraw; const float* vfirst; };
__global__ __launch_bounds__(256) void lora2_kernel(L2Args args)
{
    L2Desc dz = args.d[blockIdx.z];
    const int tid = threadIdx.x;
    const int w = tid >> 6, lane = tid & 63;
    const int wr = w >> 1, wc = w & 1;
    const int quad = lane >> 4, l16 = lane & 15;
    const int m0 = blockIdx.x * 128, n0 = blockIdx.y * 128;
    const int K = dz.K;

    f32x4 zero = {0.f, 0.f, 0.f, 0.f};
    f32x4 acc[4][4];
#pragma unroll
    for (int i = 0; i < 4; i++)
#pragma unroll
        for (int j = 0; j < 4; j++) acc[i][j] = zero;

    const bf16* Abase = dz.A  + (size_t)(m0 + wr * 64 + l16) * K + quad * 8;
    const bf16* Bbase = dz.BT + (size_t)(n0 + wc * 64 + l16) * K + quad * 8;

    for (int k0 = 0; k0 < K; k0 += 32) {
        bf16x8 af[4], bfr[4];
#pragma unroll
        for (int mi = 0; mi < 4; mi++)
            af[mi] = *reinterpret_cast<const bf16x8*>(Abase + (size_t)(mi * 16) * K + k0);
#pragma unroll
        for (int ni = 0; ni < 4; ni++)
            bfr[ni] = *reinterpret_cast<const bf16x8*>(Bbase + (size_t)(ni * 16) * K + k0);
#pragma unroll
        for (int mi = 0; mi < 4; mi++)
#pragma unroll
            for (int ni = 0; ni < 4; ni++)
                acc[mi][ni] = __builtin_amdgcn_mfma_f32_16x16x32_bf16(af[mi], bfr[ni], acc[mi][ni], 0, 0, 0);
    }

#pragma unroll
    for (int mi = 0; mi < 4; mi++)
#pragma unroll
        for (int ni = 0; ni < 4; ni++)
#pragma unroll
            for (int rg = 0; rg < 4; rg++) {
                int m = m0 + wr * 64 + mi * 16 + quad * 4 + rg;
                int n = n0 + wc * 64 + ni * 16 + l16;
                float v = acc[mi][ni][rg];
                size_t idx = (size_t)m * 1024 + n;
                if (dz.mode == 4) {
                    float xx = v + dz.bias[n];
                    float ww = -log1pf(expf(-xx)) - 0.5f;   // -softplus(-x) - 0.5
                    dz.outF[idx] = expf(-expf(ww));
                } else if (dz.mode == 5) {
                    float xx = v + dz.bias[n];
                    dz.outF[idx] = 1.f / (1.f + expf(-xx));
                } else if (dz.mode == 6) {
                    float gate = 1.f / (1.f + expf(-(v + dz.bias[n])));
                    float vr = args.vraw[idx];
                    dz.outF[idx] = vr + (args.vfirst[idx] - vr) * gate;
                } else {
                    dz.outF[idx] = v;
                }
            }
}

// ---------------- final output projection ----------------
__global__ __launch_bounds__(256) void final_kernel(const bf16* __restrict__ A, const bf16* __restrict__ BT,
                                                    float* __restrict__ out)
{
    gemm_tile(A, BT, 1024, blockIdx.x * 128, blockIdx.y * 128,
              [&](int m, int n, float v) { out[(size_t)m * 1024 + n] = v; });
}

// ---------------- pack: kk norm, k scale, r/d copy-in -> contiguous PK block per (bh,t) ----------------
__global__ __launch_bounds__(256) void pack_kernel(
    float* __restrict__ k, const float* __restrict__ a, const float* __restrict__ r,
    const float* __restrict__ v, const float* __restrict__ dw,
    const float* __restrict__ kkw, const float* __restrict__ kaw,
    float* __restrict__ PK)
{
    int tid = threadIdx.x;
    int wave = tid >> 6, lane = tid & 63;
    int idx = blockIdx.x * 4 + wave;        // (b*TT+t)*HH + h
    size_t off = (size_t)idx * 64 + lane;
    int c = (idx & 15) * 64 + lane;
    float kraw = k[off];
    float av = a[off];
    float kkv = kraw * kkw[c];
    float s = kkv * kkv;
#pragma unroll
    for (int m = 32; m; m >>= 1) s += __shfl_xor(s, m);
    float kkn = kkv / fmaxf(sqrtf(s), 1e-12f);
    float ks = kraw * (1.f + (av - 1.f) * kaw[c]);
    k[off] = ks;                            // write-back for gn_kernel
    float bb = kkn * av;
    float rv = r[off];
    float dv = dw[off];
    float bt = bb * rv, ct = ks * rv;
#pragma unroll
    for (int m = 32; m; m >>= 1) { bt += __shfl_xor(bt, m); ct += __shfl_xor(ct, m); }
    int b = idx >> 14;                      // / (TT*HH)
    int h = idx & 15;
    int t = (idx >> 4) & (TT - 1);
    size_t sidx = (size_t)(b * HH + h) * TT + t;
    float* pw = PK + sidx * PKS;
    pw[lane] = ks; pw[64 + lane] = kkn; pw[128 + lane] = bb; pw[192 + lane] = v[off];
    pw[256 + lane] = rv; pw[320 + lane] = dv;
    if (lane == 0) { pw[384] = bt; pw[385] = ct; }
}

// ---------------- sequential state recurrence: producer/consumer, 4-set unpinned (round-13) ----------------
struct SetR { f32x4 q, d, r, k, b; float vi; float2 bc; };

__device__ __forceinline__ void ds_load_set(SetR& s, const char* slot, int c16, int row)
{
    s.q  = *(const f32x4*)(slot + 256  + c16);   // kk
    s.d  = *(const f32x4*)(slot + 1280 + c16);   // decay
    s.r  = *(const f32x4*)(slot + 1024 + c16);   // r
    s.k  = *(const f32x4*)(slot + 0    + c16);   // k (scaled)
    s.b  = *(const f32x4*)(slot + 512  + c16);   // bb
    s.vi = *(const float*)(slot + 768 + row * 4);
    s.bc = *(const float2*)(slot + 1536);
}

__device__ __forceinline__ float step4(const SetR& sd, f32x4& S)
{
    f32x4 Sd   = S * sd.d;
    f32x4 sacv = S * sd.q;
    f32x4 oacv = Sd * sd.r;
    float sar = (sacv[0] + sacv[1]) + (sacv[2] + sacv[3]);
    float od  = (oacv[0] + oacv[1]) + (oacv[2] + oacv[3]);
    sar = hex_add(sar);
    od  = hex_add(od);
    float sa = -sar;
    float o = fmaf(sd.vi, sd.bc.y, fmaf(sa, sd.bc.x, od));
    S = Sd + sa * sd.b + sd.vi * sd.k;
    return o;
}

__global__ __launch_bounds__(256, 1) void scan_kernel(
    const float* __restrict__ PK, float* __restrict__ ybuf)
{
    __shared__ __align__(16) char ring[NCH * CHB];   // 4 chunks x 8 steps x 2KB = 64KB
    const int tid = threadIdx.x;
    const int wid = tid >> 6, lane = tid & 63;
    // XCD-grouped bijective decode (grid 512): all 16 row-blocks of a head on one XCD.
    const int xcd = blockIdx.x & 7, kk = blockIdx.x >> 3;
    const int bh = xcd * 4 + (kk >> 4);      // 0..31
    const int wq = kk & 15;                  // row-block 0..15
    const int b = bh >> 4, h = bh & 15;
    const int row = wq * 4 + (lane >> 4);    // 0..63 (compute wave semantics)
    const int c = lane & 15;
    const int c16 = c * 16;

    const char* base = (const char*)(PK + (size_t)bh * TT * PKS);
    const char* g1 = base + lane * 16;          // bytes 0..1023 of each step block
    const char* g2 = g1 + 1024;                 // bytes 1024..2047 (tail waste benign)

    auto stage_chunk = [&](int ci) {
        const char* p1 = g1 + (size_t)ci * CH * PKB;
        const char* p2 = g2 + (size_t)ci * CH * PKB;
        char* s = ring + (ci & (NCH - 1)) * CHB;
        for (int j = wid - 1; j < CH; j += 3) {
            gload_lds16(p1 + (size_t)j * PKB, s + j * STEPB);
            gload_lds16(p2 + (size_t)j * PKB, s + j * STEPB + 1024);
        }
    };

    if (wid > 0) {
        stage_chunk(0);
        stage_chunk(1);
        stage_chunk(2);
        asm volatile("s_waitcnt vmcnt(0)" ::: "memory");   // prologue: full drain once
    }
    __builtin_amdgcn_sched_barrier(0);
    __builtin_amdgcn_s_barrier();            // publishes chunks 0-2
    __builtin_amdgcn_sched_barrier(0);

    f32x4 S = {0.f, 0.f, 0.f, 0.f};
    SetR s0, s1, s2, s3;
    if (wid == 0) {
        ds_load_set(s0, ring + 0 * STEPB, c16, row);   // step 0
        ds_load_set(s1, ring + 1 * STEPB, c16, row);   // step 1
        ds_load_set(s2, ring + 2 * STEPB, c16, row);   // step 2
    }
    float* py = ybuf + (size_t)b * TT * CC + h * 64 + row;

    for (int i = 0; i < NC; i++) {
        if (wid == 0) {
            const char* sl  = ring + (i & (NCH - 1)) * CHB;
            const char* sln = ring + ((i + 1) & (NCH - 1)) * CHB;
            float o;
            // 8 steps, 4-set rotation: load set for step t+3, compute step t. Unpinned.
            ds_load_set(s3, sl + 3 * STEPB, c16, row); o = step4(s0, S); if (c == 0) *py = o; py += CC;
            ds_load_set(s0, sl + 4 * STEPB, c16, row); o = step4(s1, S); if (c == 0) *py = o; py += CC;
            ds_load_set(s1, sl + 5 * STEPB, c16, row); o = step4(s2, S); if (c == 0) *py = o; py += CC;
            ds_load_set(s2, sl + 6 * STEPB, c16, row); o = step4(s3, S); if (c == 0) *py = o; py += CC;
            ds_load_set(s3, sl + 7 * STEPB, c16, row); o = step4(s0, S); if (c == 0) *py = o; py += CC;
            ds_load_set(s0, sln + 0 * STEPB, c16, row); o = step4(s1, S); if (c == 0) *py = o; py += CC;
            ds_load_set(s1, sln + 1 * STEPB, c16, row); o = step4(s2, S); if (c == 0) *py = o; py += CC;
            ds_load_set(s2, sln + 2 * STEPB, c16, row); o = step4(s3, S); if (c == 0) *py = o; py += CC;
            // i == NC-1: sln slots hold stale data; loaded into s0..s2, never consumed
        } else {
            if (i + 3 < NC) {
                stage_chunk(i + 3);
                if (wid == 3) asm volatile("s_waitcnt vmcnt(4)" ::: "memory");
                else          asm volatile("s_waitcnt vmcnt(6)" ::: "memory");
            } else {
                asm volatile("s_waitcnt vmcnt(0)" ::: "memory");   // epilogue drain (cheap)
            }
        }
        __builtin_amdgcn_sched_barrier(0);
        __builtin_amdgcn_s_barrier();        // publishes chunk i+2 (and older)
        __builtin_amdgcn_sched_barrier(0);
    }
}

// ---------------- groupnorm + residual + gate -> z (bf16), 4 heads/block ----------------
__global__ __launch_bounds__(256) void gn_kernel(
    const float* __restrict__ y, const float* __restrict__ r, const float* __restrict__ k,
    const float* __restrict__ v, const float* __restrict__ g,
    const float* __restrict__ lnw, const float* __restrict__ lnb,
    const float* __restrict__ rk, bf16* __restrict__ z)
{
    int tid = threadIdx.x;
    int idx = blockIdx.x * 4 + (tid >> 6);   // (b*T+t)*16 + h
    int lane = tid & 63;
    size_t off = (size_t)idx * 64 + lane;
    int c = (idx & 15) * 64 + lane;
    float yv = y[off];
    float rv = r[off], kv = k[off], vv = v[off];
    float s1 = yv, s2 = yv * yv, s3 = rv * kv * rk[c];
#pragma unroll
    for (int m = 32; m; m >>= 1) {
        s1 += __shfl_xor(s1, m);
        s2 += __shfl_xor(s2, m);
        s3 += __shfl_xor(s3, m);
    }
    float mu = s1 * (1.f / 64.f);
    float var = fmaxf(s2 * (1.f / 64.f) - mu * mu, 0.f);
    float yn = (yv - mu) * rsqrtf(var + 64e-5f) * lnw[c] + lnb[c];
    float out = (yn + s3 * vv) * g[off];
    z[off] = f2b(out);
}

// ---------------- host ----------------
extern "C" void kernel_launch(void* const* d_in, const int* in_sizes, int n_in,
                              void* d_out, int out_size, void* d_ws, size_t ws_size,
                              hipStream_t stream)
{
    const float* x       = (const float*)d_in[0];
    const float* v_first = (const float*)d_in[1];
    const float* x_r = (const float*)d_in[2];
    const float* x_w = (const float*)d_in[3];
    const float* x_k = (const float*)d_in[4];
    const float* x_v = (const float*)d_in[5];
    const float* x_a = (const float*)d_in[6];
    const float* x_g = (const float*)d_in[7];
    const float* w1 = (const float*)d_in[8];
    const float* w2 = (const float*)d_in[9];
    const float* w0 = (const float*)d_in[10];
    const float* a1 = (const float*)d_in[11];
    const float* a2 = (const float*)d_in[12];
    const float* a0 = (const float*)d_in[13];
    const float* v1 = (const float*)d_in[14];
    const float* v2 = (const float*)d_in[15];
    const float* v0 = (const float*)d_in[16];
    const float* g1 = (const float*)d_in[17];
    const float* g2 = (const float*)d_in[18];
    const float* k_k = (const float*)d_in[19];
    const float* k_a = (const float*)d_in[20];
    const float* r_k = (const float*)d_in[21];
    const float* W_r = (const float*)d_in[22];
    const float* W_k = (const float*)d_in[23];
    const float* W_v = (const float*)d_in[24];
    const float* W_o = (const float*)d_in[25];
    const float* ln_w = (const float*)d_in[26];
    const float* ln_b = (const float*)d_in[27];

    const size_t BTC = (size_t)BB * TT * CC;   // 2M
    const int M = BB * TT;                     // 2048

    char* ws = (char*)d_ws;
    size_t off = 0;
    auto alloc = [&](size_t bytes) -> char* {
        char* p = ws + off;
        off += (bytes + 255) & ~(size_t)255;
        return p;
    };

    // ---- region0: everything here is dead before pack_kernel; PK aliases it ----
    bf16* xr = (bf16*)alloc(BTC * 2);
    bf16* xw = (bf16*)alloc(BTC * 2);
    bf16* xk = (bf16*)alloc(BTC * 2);
    bf16* xv = (bf16*)alloc(BTC * 2);
    bf16* xa = (bf16*)alloc(BTC * 2);
    bf16* xg = (bf16*)alloc(BTC * 2);
    bf16* WrT = (bf16*)alloc(1024 * 1024 * 2);
    bf16* WkT = (bf16*)alloc(1024 * 1024 * 2);
    bf16* WvT = (bf16*)alloc(1024 * 1024 * 2);
    bf16* w1T = (bf16*)alloc(128 * 1024 * 2);   // 64 rows used, pad benign
    bf16* a1T = (bf16*)alloc(128 * 1024 * 2);
    bf16* v1T = (bf16*)alloc(128 * 1024 * 2);   // 32 rows used
    bf16* g1T = (bf16*)alloc(128 * 1024 * 2);
    bf16* w2T = (bf16*)alloc(1024 * 64 * 2);
    bf16* a2T = (bf16*)alloc(1024 * 64 * 2);
    bf16* v2T = (bf16*)alloc(1024 * 32 * 2);
    bf16* g2T = (bf16*)alloc(1024 * 128 * 2);
    bf16* h_w = (bf16*)alloc((size_t)M * 64 * 2);
    bf16* h_a = (bf16*)alloc((size_t)M * 64 * 2);
    bf16* h_v = (bf16*)alloc((size_t)M * 32 * 2);
    bf16* h_g = (bf16*)alloc((size_t)M * 128 * 2);

    // PK aliases region0 (~57.3 MB); continue past max(region0, PK)
    float* PK = (float*)ws;
    size_t pk_end = (size_t)BB * HH * TT * PKS * 4;   // 58,720,256
    if (off < pk_end) off = pk_end;
    off = (off + 255) & ~(size_t)255;

    // ---- live across pack/scan ----
    bf16* WoT = (bf16*)alloc(1024 * 1024 * 2);
    float* rbuf = (float*)alloc(BTC * 4);
    float* kbuf = (float*)alloc(BTC * 4);
    float* vraw = (float*)alloc(BTC * 4);   // reused as ybuf after lora2
    float* vbuf = (float*)alloc(BTC * 4);
    float* dbuf = (float*)alloc(BTC * 4);   // reused as zbuf (bf16) after scan
    float* abuf = (float*)alloc(BTC * 4);
    float* gbuf = (float*)alloc(BTC * 4);

    float* ybuf = vraw;
    bf16*  zbuf = (bf16*)dbuf;

    (void)in_sizes; (void)n_in; (void)out_size; (void)ws_size;

    // 1) transposes + token-shift mix in one launch
    PrepArgs pa;
    pa.d[0]  = {W_r, WrT, 1024, 1024};
    pa.d[1]  = {W_k, WkT, 1024, 1024};
    pa.d[2]  = {W_v, WvT, 1024, 1024};
    pa.d[3]  = {W_o, WoT, 1024, 1024};
    pa.d[4]  = {w1, w1T, 1024, 64};
    pa.d[5]  = {a1, a1T, 1024, 64};
    pa.d[6]  = {v1, v1T, 1024, 32};
    pa.d[7]  = {g1, g1T, 1024, 128};
    pa.d[8]  = {w2, w2T, 64, 1024};
    pa.d[9]  = {a2, a2T, 64, 1024};
    pa.d[10] = {v2, v2T, 32, 1024};
    pa.d[11] = {g2, g2T, 128, 1024};
    pa.x = x; pa.vfirst = v_first;
    pa.mr = x_r; pa.mw = x_w; pa.mk = x_k; pa.mv = x_v; pa.ma = x_a; pa.mg = x_g;
    pa.xr = xr; pa.xw = xw; pa.xk = xk; pa.xv = xv; pa.xa = xa; pa.xg = xg;
    pa.vout = (float*)d_out + BTC;
    prep_kernel<<<dim3(32, 32, 13), 256, 0, stream>>>(pa);

    // 2) big projections r/k/v + lora stage 1, one launch
    ProjArgs pj;
    pj.A[0] = xr; pj.A[1] = xk; pj.A[2] = xv;
    pj.BT[0] = WrT; pj.BT[1] = WkT; pj.BT[2] = WvT;
    pj.out[0] = rbuf; pj.out[1] = kbuf; pj.out[2] = vraw;
    pj.d[0] = {xw, w1T, h_w, 64, 2};
    pj.d[1] = {xa, a1T, h_a, 64, 0};
    pj.d[2] = {xv, v1T, h_v, 32, 0};
    pj.d[3] = {xg, g1T, h_g, 128, 3};
    proj_kernel<<<dim3(16, 8, 7), 256, 0, stream>>>(pj);

    // 3) lora stage 2 + g2 (register-direct small-K GEMM)
    L2Args l2;
    l2.d[0] = {h_w, w2T, w0, dbuf, 64, 4};
    l2.d[1] = {h_a, a2T, a0, abuf, 64, 5};
    l2.d[2] = {h_v, v2T, v0, vbuf, 32, 6};
    l2.d[3] = {h_g, g2T, nullptr, gbuf, 128, 0};
    l2.vraw = vraw; l2.vfirst = v_first;
    lora2_kernel<<<dim3(16, 8, 4), 256, 0, stream>>>(l2);

    // 4) pack (contiguous PK blocks incl. r/d/bt/ct; writes scaled k back to kbuf)
    pack_kernel<<<BB * TT * HH / 4, 256, 0, stream>>>(kbuf, abuf, rbuf, vbuf, dbuf, k_k, k_a, PK);

    // 5) sequential recurrence (round-13 best: producer/consumer, 4-set unpinned)
    scan_kernel<<<BB * HH * 16, 256, 0, stream>>>(PK, ybuf);

    // 6) groupnorm + residual + gate (writes zbuf = dbuf region)
    gn_kernel<<<BB * TT * HH / 4, 256, 0, stream>>>(ybuf, rbuf, kbuf, vbuf, gbuf, ln_w, ln_b, r_k, zbuf);

    // 7) output projection -> d_out (f32)
    final_kernel<<<dim3(16, 8), 256, 0, stream>>>(zbuf, WoT, (float*)d_out);
}

// Round 16
// 395.034 us; speedup vs baseline: 1.3551x; 1.0417x over previous
//
#include <hip/hip_runtime.h>
#include <hip/hip_bf16.h>
#include <cstdint>
#include <cstddef>

typedef __hip_bfloat16 bf16;
typedef __bf16 bf16x8 __attribute__((ext_vector_type(8)));
typedef float f32x4 __attribute__((ext_vector_type(4)));

#define BB 2
#define TT 1024
#define CC 1024
#define HH 16
#define PKS 448   // floats per (bh,t) block: k[64] kk[64] bb[64] v[64] r[64] d[64] bt ct pad
#define PKB 1792  // bytes per block (448*4)
#define CH 8      // steps per chunk
#define NCH 4     // chunks in LDS ring
#define STEPB 2048  // bytes per step slot in LDS
#define CHB (CH * STEPB)
#define NC (TT / CH)

__device__ __forceinline__ bf16 f2b(float v){ return __float2bfloat16(v); }
__device__ __forceinline__ unsigned short f2bu(float v){
    bf16 b = __float2bfloat16(v);
    return *reinterpret_cast<unsigned short*>(&b);
}

// 16-lane-row sum via DPP only (quad xor1, xor2, half_mirror ^4, row_mirror ^8).
__device__ __forceinline__ float hex_add(float x) {
    x += __int_as_float(__builtin_amdgcn_mov_dpp(__float_as_int(x), 0xB1, 0xF, 0xF, true));
    x += __int_as_float(__builtin_amdgcn_mov_dpp(__float_as_int(x), 0x4E, 0xF, 0xF, true));
    x += __int_as_float(__builtin_amdgcn_mov_dpp(__float_as_int(x), 0x141, 0xF, 0xF, true));
    x += __int_as_float(__builtin_amdgcn_mov_dpp(__float_as_int(x), 0x140, 0xF, 0xF, true));
    return x;
}

// async global -> LDS, 16B per lane (dest = wave-uniform base + lane*16, src per-lane)
typedef __attribute__((address_space(3))) void as3_void;
typedef __attribute__((address_space(1))) const void as1_void;
__device__ __forceinline__ void gload_lds16(const void* g, void* l) {
    __builtin_amdgcn_global_load_lds((as1_void*)g, (as3_void*)l, 16, 0, 0);
}

// ---------------- prep: 12 weight transposes + token-shift mix in ONE launch ----------------
struct TrDesc { const float* in; bf16* out; int R, S; };
struct PrepArgs {
    TrDesc d[12];
    const float* x; const float* vfirst;
    const float *mr, *mw, *mk, *mv, *ma, *mg;
    bf16 *xr, *xw, *xk, *xv, *xa, *xg;
    float* vout;
};

__global__ __launch_bounds__(256) void prep_kernel(PrepArgs args)
{
    if (blockIdx.z < 12) {
        TrDesc t = args.d[blockIdx.z];
        __shared__ float tile[32][33];
        int s0 = blockIdx.x * 32, r0 = blockIdx.y * 32;
        if (s0 >= t.S || r0 >= t.R) return;      // block-uniform early exit
        int tx = threadIdx.x & 31, ty = threadIdx.x >> 5;
#pragma unroll
        for (int i = 0; i < 4; i++) {
            int r = r0 + ty + i * 8, s = s0 + tx;
            if (r < t.R && s < t.S) tile[ty + i * 8][tx] = t.in[(size_t)r * t.S + s];
        }
        __syncthreads();
#pragma unroll
        for (int i = 0; i < 4; i++) {
            int s = s0 + ty + i * 8, r = r0 + tx;
            if (s < t.S && r < t.R) t.out[(size_t)s * t.R + r] = f2b(tile[tx][ty + i * 8]);
        }
        return;
    }
    // z == 12: token-shift mix, 2 rows per block, VECTORIZED (G13):
    // thread owns 4 consecutive channels; float4 loads, packed ushort4 bf16 stores
    // (8B/lane = 512B per wave-store vs 128B scalar).
    int bid = blockIdx.y * 32 + blockIdx.x;
    int c4 = threadIdx.x * 4;                  // 256 threads x 4 = 1024 channels
    float4 m_r = *(const float4*)(args.mr + c4);
    float4 m_w = *(const float4*)(args.mw + c4);
    float4 m_k = *(const float4*)(args.mk + c4);
    float4 m_v = *(const float4*)(args.mv + c4);
    float4 m_a = *(const float4*)(args.ma + c4);
    float4 m_g = *(const float4*)(args.mg + c4);
#pragma unroll
    for (int rr = 0; rr < 2; rr++) {
        int row = bid * 2 + rr;
        int t = row & (TT - 1);
        size_t base = (size_t)row * CC + c4;
        float4 xc = *(const float4*)(args.x + base);
        float4 xp = (t > 0) ? *(const float4*)(args.x + base - CC)
                            : make_float4(0.f, 0.f, 0.f, 0.f);
        float4 d = make_float4(xp.x - xc.x, xp.y - xc.y, xp.z - xc.z, xp.w - xc.w);
        *(float4*)(args.vout + base) = *(const float4*)(args.vfirst + base);
        auto packst = [&](bf16* dst, const float4& m) {
            ushort4 o;
            o.x = f2bu(fmaf(d.x, m.x, xc.x));
            o.y = f2bu(fmaf(d.y, m.y, xc.y));
            o.z = f2bu(fmaf(d.z, m.z, xc.z));
            o.w = f2bu(fmaf(d.w, m.w, xc.w));
            *reinterpret_cast<ushort4*>(dst + base) = o;
        };
        packst(args.xr, m_r);
        packst(args.xw, m_w);
        packst(args.xk, m_k);
        packst(args.xv, m_v);
        packst(args.xa, m_a);
        packst(args.xg, m_g);
    }
}

// ---------------- shared MFMA tile body: 2-phase double-buffered (round-10 proven) ----------------
template <class EmitF>
__device__ __forceinline__ void gemm_tile(const bf16* __restrict__ A, const bf16* __restrict__ BT,
                                          int K, int m0, int n0, EmitF emit)
{
    __shared__ __align__(16) bf16 Atile[2][128 * 32];
    __shared__ __align__(16) bf16 Btile[2][128 * 32];
    int tid = threadIdx.x;
    int w = tid >> 6, lane = tid & 63;
    int wr = w >> 1, wc = w & 1;
    int quad = lane >> 4, l16 = lane & 15;

    f32x4 zero = {0.f, 0.f, 0.f, 0.f};
    f32x4 acc[4][4];
#pragma unroll
    for (int i = 0; i < 4; i++)
#pragma unroll
        for (int j = 0; j < 4; j++) acc[i][j] = zero;

    int rr = lane >> 2;            // 0..15
    int cs = lane & 3;             // chunk slot in LDS
    int ra0 = w * 32 + rr;         // rows this lane sources
    int ra1 = ra0 + 16;
    int cg0 = cs ^ ((ra0 >> 1) & 3);   // global chunk (XOR swizzle on SOURCE side)
    int cg1 = cs ^ ((ra1 >> 1) & 3);

    const bf16* Ar0 = A  + (size_t)(m0 + ra0) * K + cg0 * 8;
    const bf16* Ar1 = A  + (size_t)(m0 + ra1) * K + cg1 * 8;
    const bf16* Br0 = BT + (size_t)(n0 + ra0) * K + cg0 * 8;
    const bf16* Br1 = BT + (size_t)(n0 + ra1) * K + cg1 * 8;

    auto stage = [&](int k0, int buf) {
        bf16* atb = Atile[buf] + w * 1024;   // wave-uniform LDS base (+lane*16B implicit)
        bf16* btb = Btile[buf] + w * 1024;
        gload_lds16(Ar0 + k0, atb);
        gload_lds16(Ar1 + k0, atb + 512);
        gload_lds16(Br0 + k0, btb);
        gload_lds16(Br1 + k0, btb + 512);
    };

    stage(0, 0);
    __syncthreads();               // tile 0 resident

    int cur = 0;
    for (int k0 = 0; k0 < K; k0 += 32) {
        if (k0 + 32 < K) stage(k0 + 32, cur ^ 1);   // in-flight across the compute below

        bf16x8 af[4], bfr[4];
#pragma unroll
        for (int mi = 0; mi < 4; mi++) {
            int m = wr * 64 + mi * 16 + l16;
            int c2 = quad ^ ((m >> 1) & 3);
            af[mi] = *reinterpret_cast<const bf16x8*>(&Atile[cur][m * 32 + c2 * 8]);
        }
#pragma unroll
        for (int ni = 0; ni < 4; ni++) {
            int n = wc * 64 + ni * 16 + l16;
            int c2 = quad ^ ((n >> 1) & 3);
            bfr[ni] = *reinterpret_cast<const bf16x8*>(&Btile[cur][n * 32 + c2 * 8]);
        }
#pragma unroll
        for (int mi = 0; mi < 4; mi++)
#pragma unroll
            for (int ni = 0; ni < 4; ni++)
                acc[mi][ni] = __builtin_amdgcn_mfma_f32_16x16x32_bf16(af[mi], bfr[ni], acc[mi][ni], 0, 0, 0);

        __syncthreads();           // drains vmcnt(0)+lgkm: next tile resident, reads done
        cur ^= 1;
    }

#pragma unroll
    for (int mi = 0; mi < 4; mi++)
#pragma unroll
        for (int ni = 0; ni < 4; ni++)
#pragma unroll
            for (int rg = 0; rg < 4; rg++) {
                int m = m0 + wr * 64 + mi * 16 + quad * 4 + rg;
                int n = n0 + wc * 64 + ni * 16 + l16;
                emit(m, n, acc[mi][ni][rg]);
            }
}

// ---------------- merged projections: big r/k/v (z 0..2) + lora stage 1 (z 3..6) ----------------
struct L1Desc { const bf16* A; const bf16* BT; bf16* outB; int N; int mode; }; // 0 plain, 2 tanh, 3 sigmoid
struct ProjArgs { const bf16* A[3]; const bf16* BT[3]; float* out[3]; L1Desc d[4]; };

__global__ __launch_bounds__(256) void proj_kernel(ProjArgs args)
{
    int z = blockIdx.z;
    if (z < 3) {
        float* out = args.out[z];
        gemm_tile(args.A[z], args.BT[z], 1024, blockIdx.x * 128, blockIdx.y * 128,
                  [&](int m, int n, float v) { out[(size_t)m * 1024 + n] = v; });
        return;
    }
    if (blockIdx.y) return;                   // lora1 output is <=128 wide (block-uniform exit)
    L1Desc dz = args.d[z - 3];
    gemm_tile(dz.A, dz.BT, 1024, blockIdx.x * 128, 0,
              [&](int m, int n, float v) {
                  if (n < dz.N) {
                      float r = (dz.mode == 2) ? tanhf(v)
                              : (dz.mode == 3) ? 1.f / (1.f + expf(-v)) : v;
                      dz.outB[(size_t)m * dz.N + n] = f2b(r);
                  }
              });
}

// ---------------- lora stage 2 (+g2): REGISTER-DIRECT small-K GEMM (round-15) ----------------
struct L2Desc { const bf16* A; const bf16* BT; const float* bias; float* outF; int K; int mode; };
struct L2Args { L2Desc d[4]; const float* vraw; const float* vfirst; };
__global__ __launch_bounds__(256) void lora2_kernel(L2Args args)
{
    L2Desc dz = args.d[blockIdx.z];
    const int tid = threadIdx.x;
    const int w = tid >> 6, lane = tid & 63;
    const int wr = w >> 1, wc = w & 1;
    const int quad = lane >> 4, l16 = lane & 15;
    const int m0 = blockIdx.x * 128, n0 = blockIdx.y * 128;
    const int K = dz.K;

    f32x4 zero = {0.f, 0.f, 0.f, 0.f};
    f32x4 acc[4][4];
#pragma unroll
    for (int i = 0; i < 4; i++)
#pragma unroll
        for (int j = 0; j < 4; j++) acc[i][j] = zero;

    const bf16* Abase = dz.A  + (size_t)(m0 + wr * 64 + l16) * K + quad * 8;
    const bf16* Bbase = dz.BT + (size_t)(n0 + wc * 64 + l16) * K + quad * 8;

    for (int k0 = 0; k0 < K; k0 += 32) {
        bf16x8 af[4], bfr[4];
#pragma unroll
        for (int mi = 0; mi < 4; mi++)
            af[mi] = *reinterpret_cast<const bf16x8*>(Abase + (size_t)(mi * 16) * K + k0);
#pragma unroll
        for (int ni = 0; ni < 4; ni++)
            bfr[ni] = *reinterpret_cast<const bf16x8*>(Bbase + (size_t)(ni * 16) * K + k0);
#pragma unroll
        for (int mi = 0; mi < 4; mi++)
#pragma unroll
            for (int ni = 0; ni < 4; ni++)
                acc[mi][ni] = __builtin_amdgcn_mfma_f32_16x16x32_bf16(af[mi], bfr[ni], acc[mi][ni], 0, 0, 0);
    }

#pragma unroll
    for (int mi = 0; mi < 4; mi++)
#pragma unroll
        for (int ni = 0; ni < 4; ni++)
#pragma unroll
            for (int rg = 0; rg < 4; rg++) {
                int m = m0 + wr * 64 + mi * 16 + quad * 4 + rg;
                int n = n0 + wc * 64 + ni * 16 + l16;
                float v = acc[mi][ni][rg];
                size_t idx = (size_t)m * 1024 + n;
                if (dz.mode == 4) {
                    float xx = v + dz.bias[n];
                    float ww = -log1pf(expf(-xx)) - 0.5f;   // -softplus(-x) - 0.5
                    dz.outF[idx] = expf(-expf(ww));
                } else if (dz.mode == 5) {
                    float xx = v + dz.bias[n];
                    dz.outF[idx] = 1.f / (1.f + expf(-xx));
                } else if (dz.mode == 6) {
                    float gate = 1.f / (1.f + expf(-(v + dz.bias[n])));
                    float vr = args.vraw[idx];
                    dz.outF[idx] = vr + (args.vfirst[idx] - vr) * gate;
                } else {
                    dz.outF[idx] = v;
                }
            }
}

// ---------------- final output projection ----------------
__global__ __launch_bounds__(256) void final_kernel(const bf16* __restrict__ A, const bf16* __restrict__ BT,
                                                    float* __restrict__ out)
{
    gemm_tile(A, BT, 1024, blockIdx.x * 128, blockIdx.y * 128,
              [&](int m, int n, float v) { out[(size_t)m * 1024 + n] = v; });
}

// ---------------- pack: kk norm, k scale, r/d copy-in -> contiguous PK block per (bh,t) ----------------
__global__ __launch_bounds__(256) void pack_kernel(
    float* __restrict__ k, const float* __restrict__ a, const float* __restrict__ r,
    const float* __restrict__ v, const float* __restrict__ dw,
    const float* __restrict__ kkw, const float* __restrict__ kaw,
    float* __restrict__ PK)
{
    int tid = threadIdx.x;
    int wave = tid >> 6, lane = tid & 63;
    int idx = blockIdx.x * 4 + wave;        // (b*TT+t)*HH + h
    size_t off = (size_t)idx * 64 + lane;
    int c = (idx & 15) * 64 + lane;
    float kraw = k[off];
    float av = a[off];
    float kkv = kraw * kkw[c];
    float s = kkv * kkv;
#pragma unroll
    for (int m = 32; m; m >>= 1) s += __shfl_xor(s, m);
    float kkn = kkv / fmaxf(sqrtf(s), 1e-12f);
    float ks = kraw * (1.f + (av - 1.f) * kaw[c]);
    k[off] = ks;                            // write-back for gn_kernel
    float bb = kkn * av;
    float rv = r[off];
    float dv = dw[off];
    float bt = bb * rv, ct = ks * rv;
#pragma unroll
    for (int m = 32; m; m >>= 1) { bt += __shfl_xor(bt, m); ct += __shfl_xor(ct, m); }
    int b = idx >> 14;                      // / (TT*HH)
    int h = idx & 15;
    int t = (idx >> 4) & (TT - 1);
    size_t sidx = (size_t)(b * HH + h) * TT + t;
    float* pw = PK + sidx * PKS;
    pw[lane] = ks; pw[64 + lane] = kkn; pw[128 + lane] = bb; pw[192 + lane] = v[off];
    pw[256 + lane] = rv; pw[320 + lane] = dv;
    if (lane == 0) { pw[384] = bt; pw[385] = ct; }
}

// ---------------- sequential state recurrence: producer/consumer, 4-set unpinned (round-13) ----------------
struct SetR { f32x4 q, d, r, k, b; float vi; float2 bc; };

__device__ __forceinline__ void ds_load_set(SetR& s, const char* slot, int c16, int row)
{
    s.q  = *(const f32x4*)(slot + 256  + c16);   // kk
    s.d  = *(const f32x4*)(slot + 1280 + c16);   // decay
    s.r  = *(const f32x4*)(slot + 1024 + c16);   // r
    s.k  = *(const f32x4*)(slot + 0    + c16);   // k (scaled)
    s.b  = *(const f32x4*)(slot + 512  + c16);   // bb
    s.vi = *(const float*)(slot + 768 + row * 4);
    s.bc = *(const float2*)(slot + 1536);
}

__device__ __forceinline__ float step4(const SetR& sd, f32x4& S)
{
    f32x4 Sd   = S * sd.d;
    f32x4 sacv = S * sd.q;
    f32x4 oacv = Sd * sd.r;
    float sar = (sacv[0] + sacv[1]) + (sacv[2] + sacv[3]);
    float od  = (oacv[0] + oacv[1]) + (oacv[2] + oacv[3]);
    sar = hex_add(sar);
    od  = hex_add(od);
    float sa = -sar;
    float o = fmaf(sd.vi, sd.bc.y, fmaf(sa, sd.bc.x, od));
    S = Sd + sa * sd.b + sd.vi * sd.k;
    return o;
}

__global__ __launch_bounds__(256, 1) void scan_kernel(
    const float* __restrict__ PK, float* __restrict__ ybuf)
{
    __shared__ __align__(16) char ring[NCH * CHB];   // 4 chunks x 8 steps x 2KB = 64KB
    const int tid = threadIdx.x;
    const int wid = tid >> 6, lane = tid & 63;
    // XCD-grouped bijective decode (grid 512): all 16 row-blocks of a head on one XCD.
    const int xcd = blockIdx.x & 7, kk = blockIdx.x >> 3;
    const int bh = xcd * 4 + (kk >> 4);      // 0..31
    const int wq = kk & 15;                  // row-block 0..15
    const int b = bh >> 4, h = bh & 15;
    const int row = wq * 4 + (lane >> 4);    // 0..63 (compute wave semantics)
    const int c = lane & 15;
    const int c16 = c * 16;

    const char* base = (const char*)(PK + (size_t)bh * TT * PKS);
    const char* g1 = base + lane * 16;          // bytes 0..1023 of each step block
    const char* g2 = g1 + 1024;                 // bytes 1024..2047 (tail waste benign)

    auto stage_chunk = [&](int ci) {
        const char* p1 = g1 + (size_t)ci * CH * PKB;
        const char* p2 = g2 + (size_t)ci * CH * PKB;
        char* s = ring + (ci & (NCH - 1)) * CHB;
        for (int j = wid - 1; j < CH; j += 3) {
            gload_lds16(p1 + (size_t)j * PKB, s + j * STEPB);
            gload_lds16(p2 + (size_t)j * PKB, s + j * STEPB + 1024);
        }
    };

    if (wid > 0) {
        stage_chunk(0);
        stage_chunk(1);
        stage_chunk(2);
        asm volatile("s_waitcnt vmcnt(0)" ::: "memory");   // prologue: full drain once
    }
    __builtin_amdgcn_sched_barrier(0);
    __builtin_amdgcn_s_barrier();            // publishes chunks 0-2
    __builtin_amdgcn_sched_barrier(0);

    f32x4 S = {0.f, 0.f, 0.f, 0.f};
    SetR s0, s1, s2, s3;
    if (wid == 0) {
        ds_load_set(s0, ring + 0 * STEPB, c16, row);   // step 0
        ds_load_set(s1, ring + 1 * STEPB, c16, row);   // step 1
        ds_load_set(s2, ring + 2 * STEPB, c16, row);   // step 2
    }
    float* py = ybuf + (size_t)b * TT * CC + h * 64 + row;

    for (int i = 0; i < NC; i++) {
        if (wid == 0) {
            const char* sl  = ring + (i & (NCH - 1)) * CHB;
            const char* sln = ring + ((i + 1) & (NCH - 1)) * CHB;
            float o;
            // 8 steps, 4-set rotation: load set for step t+3, compute step t. Unpinned.
            ds_load_set(s3, sl + 3 * STEPB, c16, row); o = step4(s0, S); if (c == 0) *py = o; py += CC;
            ds_load_set(s0, sl + 4 * STEPB, c16, row); o = step4(s1, S); if (c == 0) *py = o; py += CC;
            ds_load_set(s1, sl + 5 * STEPB, c16, row); o = step4(s2, S); if (c == 0) *py = o; py += CC;
            ds_load_set(s2, sl + 6 * STEPB, c16, row); o = step4(s3, S); if (c == 0) *py = o; py += CC;
            ds_load_set(s3, sl + 7 * STEPB, c16, row); o = step4(s0, S); if (c == 0) *py = o; py += CC;
            ds_load_set(s0, sln + 0 * STEPB, c16, row); o = step4(s1, S); if (c == 0) *py = o; py += CC;
            ds_load_set(s1, sln + 1 * STEPB, c16, row); o = step4(s2, S); if (c == 0) *py = o; py += CC;
            ds_load_set(s2, sln + 2 * STEPB, c16, row); o = step4(s3, S); if (c == 0) *py = o; py += CC;
            // i == NC-1: sln slots hold stale data; loaded into s0..s2, never consumed
        } else {
            if (i + 3 < NC) {
                stage_chunk(i + 3);
                if (wid == 3) asm volatile("s_waitcnt vmcnt(4)" ::: "memory");
                else          asm volatile("s_waitcnt vmcnt(6)" ::: "memory");
            } else {
                asm volatile("s_waitcnt vmcnt(0)" ::: "memory");   // epilogue drain (cheap)
            }
        }
        __builtin_amdgcn_sched_barrier(0);
        __builtin_amdgcn_s_barrier();        // publishes chunk i+2 (and older)
        __builtin_amdgcn_sched_barrier(0);
    }
}

// ---------------- groupnorm + residual + gate -> z (bf16), 4 heads/block ----------------
__global__ __launch_bounds__(256) void gn_kernel(
    const float* __restrict__ y, const float* __restrict__ r, const float* __restrict__ k,
    const float* __restrict__ v, const float* __restrict__ g,
    const float* __restrict__ lnw, const float* __restrict__ lnb,
    const float* __restrict__ rk, bf16* __restrict__ z)
{
    int tid = threadIdx.x;
    int idx = blockIdx.x * 4 + (tid >> 6);   // (b*T+t)*16 + h
    int lane = tid & 63;
    size_t off = (size_t)idx * 64 + lane;
    int c = (idx & 15) * 64 + lane;
    float yv = y[off];
    float rv = r[off], kv = k[off], vv = v[off];
    float s1 = yv, s2 = yv * yv, s3 = rv * kv * rk[c];
#pragma unroll
    for (int m = 32; m; m >>= 1) {
        s1 += __shfl_xor(s1, m);
        s2 += __shfl_xor(s2, m);
        s3 += __shfl_xor(s3, m);
    }
    float mu = s1 * (1.f / 64.f);
    float var = fmaxf(s2 * (1.f / 64.f) - mu * mu, 0.f);
    float yn = (yv - mu) * rsqrtf(var + 64e-5f) * lnw[c] + lnb[c];
    float out = (yn + s3 * vv) * g[off];
    z[off] = f2b(out);
}

// ---------------- host ----------------
extern "C" void kernel_launch(void* const* d_in, const int* in_sizes, int n_in,
                              void* d_out, int out_size, void* d_ws, size_t ws_size,
                              hipStream_t stream)
{
    const float* x       = (const float*)d_in[0];
    const float* v_first = (const float*)d_in[1];
    const float* x_r = (const float*)d_in[2];
    const float* x_w = (const float*)d_in[3];
    const float* x_k = (const float*)d_in[4];
    const float* x_v = (const float*)d_in[5];
    const float* x_a = (const float*)d_in[6];
    const float* x_g = (const float*)d_in[7];
    const float* w1 = (const float*)d_in[8];
    const float* w2 = (const float*)d_in[9];
    const float* w0 = (const float*)d_in[10];
    const float* a1 = (const float*)d_in[11];
    const float* a2 = (const float*)d_in[12];
    const float* a0 = (const float*)d_in[13];
    const float* v1 = (const float*)d_in[14];
    const float* v2 = (const float*)d_in[15];
    const float* v0 = (const float*)d_in[16];
    const float* g1 = (const float*)d_in[17];
    const float* g2 = (const float*)d_in[18];
    const float* k_k = (const float*)d_in[19];
    const float* k_a = (const float*)d_in[20];
    const float* r_k = (const float*)d_in[21];
    const float* W_r = (const float*)d_in[22];
    const float* W_k = (const float*)d_in[23];
    const float* W_v = (const float*)d_in[24];
    const float* W_o = (const float*)d_in[25];
    const float* ln_w = (const float*)d_in[26];
    const float* ln_b = (const float*)d_in[27];

    const size_t BTC = (size_t)BB * TT * CC;   // 2M
    const int M = BB * TT;                     // 2048

    char* ws = (char*)d_ws;
    size_t off = 0;
    auto alloc = [&](size_t bytes) -> char* {
        char* p = ws + off;
        off += (bytes + 255) & ~(size_t)255;
        return p;
    };

    // ---- region0: everything here is dead before pack_kernel; PK aliases it ----
    bf16* xr = (bf16*)alloc(BTC * 2);
    bf16* xw = (bf16*)alloc(BTC * 2);
    bf16* xk = (bf16*)alloc(BTC * 2);
    bf16* xv = (bf16*)alloc(BTC * 2);
    bf16* xa = (bf16*)alloc(BTC * 2);
    bf16* xg = (bf16*)alloc(BTC * 2);
    bf16* WrT = (bf16*)alloc(1024 * 1024 * 2);
    bf16* WkT = (bf16*)alloc(1024 * 1024 * 2);
    bf16* WvT = (bf16*)alloc(1024 * 1024 * 2);
    bf16* w1T = (bf16*)alloc(128 * 1024 * 2);   // 64 rows used, pad benign
    bf16* a1T = (bf16*)alloc(128 * 1024 * 2);
    bf16* v1T = (bf16*)alloc(128 * 1024 * 2);   // 32 rows used
    bf16* g1T = (bf16*)alloc(128 * 1024 * 2);
    bf16* w2T = (bf16*)alloc(1024 * 64 * 2);
    bf16* a2T = (bf16*)alloc(1024 * 64 * 2);
    bf16* v2T = (bf16*)alloc(1024 * 32 * 2);
    bf16* g2T = (bf16*)alloc(1024 * 128 * 2);
    bf16* h_w = (bf16*)alloc((size_t)M * 64 * 2);
    bf16* h_a = (bf16*)alloc((size_t)M * 64 * 2);
    bf16* h_v = (bf16*)alloc((size_t)M * 32 * 2);
    bf16* h_g = (bf16*)alloc((size_t)M * 128 * 2);

    // PK aliases region0 (~57.3 MB); continue past max(region0, PK)
    float* PK = (float*)ws;
    size_t pk_end = (size_t)BB * HH * TT * PKS * 4;   // 58,720,256
    if (off < pk_end) off = pk_end;
    off = (off + 255) & ~(size_t)255;

    // ---- live across pack/scan ----
    bf16* WoT = (bf16*)alloc(1024 * 1024 * 2);
    float* rbuf = (float*)alloc(BTC * 4);
    float* kbuf = (float*)alloc(BTC * 4);
    float* vraw = (float*)alloc(BTC * 4);   // reused as ybuf after lora2
    float* vbuf = (float*)alloc(BTC * 4);
    float* dbuf = (float*)alloc(BTC * 4);   // reused as zbuf (bf16) after scan
    float* abuf = (float*)alloc(BTC * 4);
    float* gbuf = (float*)alloc(BTC * 4);

    float* ybuf = vraw;
    bf16*  zbuf = (bf16*)dbuf;

    (void)in_sizes; (void)n_in; (void)out_size; (void)ws_size;

    // 1) transposes + token-shift mix in one launch (mix vectorized, G13)
    PrepArgs pa;
    pa.d[0]  = {W_r, WrT, 1024, 1024};
    pa.d[1]  = {W_k, WkT, 1024, 1024};
    pa.d[2]  = {W_v, WvT, 1024, 1024};
    pa.d[3]  = {W_o, WoT, 1024, 1024};
    pa.d[4]  = {w1, w1T, 1024, 64};
    pa.d[5]  = {a1, a1T, 1024, 64};
    pa.d[6]  = {v1, v1T, 1024, 32};
    pa.d[7]  = {g1, g1T, 1024, 128};
    pa.d[8]  = {w2, w2T, 64, 1024};
    pa.d[9]  = {a2, a2T, 64, 1024};
    pa.d[10] = {v2, v2T, 32, 1024};
    pa.d[11] = {g2, g2T, 128, 1024};
    pa.x = x; pa.vfirst = v_first;
    pa.mr = x_r; pa.mw = x_w; pa.mk = x_k; pa.mv = x_v; pa.ma = x_a; pa.mg = x_g;
    pa.xr = xr; pa.xw = xw; pa.xk = xk; pa.xv = xv; pa.xa = xa; pa.xg = xg;
    pa.vout = (float*)d_out + BTC;
    prep_kernel<<<dim3(32, 32, 13), 256, 0, stream>>>(pa);

    // 2) big projections r/k/v + lora stage 1, one launch
    ProjArgs pj;
    pj.A[0] = xr; pj.A[1] = xk; pj.A[2] = xv;
    pj.BT[0] = WrT; pj.BT[1] = WkT; pj.BT[2] = WvT;
    pj.out[0] = rbuf; pj.out[1] = kbuf; pj.out[2] = vraw;
    pj.d[0] = {xw, w1T, h_w, 64, 2};
    pj.d[1] = {xa, a1T, h_a, 64, 0};
    pj.d[2] = {xv, v1T, h_v, 32, 0};
    pj.d[3] = {xg, g1T, h_g, 128, 3};
    proj_kernel<<<dim3(16, 8, 7), 256, 0, stream>>>(pj);

    // 3) lora stage 2 + g2 (register-direct small-K GEMM)
    L2Args l2;
    l2.d[0] = {h_w, w2T, w0, dbuf, 64, 4};
    l2.d[1] = {h_a, a2T, a0, abuf, 64, 5};
    l2.d[2] = {h_v, v2T, v0, vbuf, 32, 6};
    l2.d[3] = {h_g, g2T, nullptr, gbuf, 128, 0};
    l2.vraw = vraw; l2.vfirst = v_first;
    lora2_kernel<<<dim3(16, 8, 4), 256, 0, stream>>>(l2);

    // 4) pack (contiguous PK blocks incl. r/d/bt/ct; writes scaled k back to kbuf)
    pack_kernel<<<BB * TT * HH / 4, 256, 0, stream>>>(kbuf, abuf, rbuf, vbuf, dbuf, k_k, k_a, PK);

    // 5) sequential recurrence (round-13 best: producer/consumer, 4-set unpinned)
    scan_kernel<<<BB * HH * 16, 256, 0, stream>>>(PK, ybuf);

    // 6) groupnorm + residual + gate (writes zbuf = dbuf region)
    gn_kernel<<<BB * TT * HH / 4, 256, 0, stream>>>(ybuf, rbuf, kbuf, vbuf, gbuf, ln_w, ln_b, r_k, zbuf);

    // 7) output projection -> d_out (f32)
    final_kernel<<<dim3(16, 8), 256, 0, stream>>>(zbuf, WoT, (float*)d_out);
}